// Round 4
// baseline (258.391 us; speedup 1.0000x reference)
//
#include <hip/hip_runtime.h>
#include <math.h>

#define T_LEN 100
#define K_LEN 25
#define DLAT 64
#define DHID 128
#define CST 68   // h2s/aggs row stride (floats); 68*4=272B keeps 16B alignment
#define AST 68   // adjacency row stride (u32)

__device__ __forceinline__ float dot4(float4 a, float4 b) {
    return a.x * b.x + a.y * b.y + a.z * b.z + a.w * b.w;
}

// Software grid barrier. SAFE only because LDS (147KB) forces 1 block/CU and
// grid <= 256 = #CUs, so every block is resident before any block waits.
__device__ __forceinline__ void grid_barrier(unsigned* cnt, unsigned* flag,
                                             unsigned nb) {
    __syncthreads();
    if (threadIdx.x == 0) {
        __threadfence();  // release: make this block's global writes visible
        unsigned t = __hip_atomic_fetch_add(cnt, 1u, __ATOMIC_ACQ_REL,
                                            __HIP_MEMORY_SCOPE_AGENT);
        if (t == nb - 1u) {
            __hip_atomic_store(flag, 1u, __ATOMIC_RELEASE,
                               __HIP_MEMORY_SCOPE_AGENT);
        } else {
            while (__hip_atomic_load(flag, __ATOMIC_ACQUIRE,
                                     __HIP_MEMORY_SCOPE_AGENT) == 0u)
                __builtin_amdgcn_s_sleep(8);
        }
        __threadfence();  // acquire: invalidate stale cached lines
    }
    __syncthreads();
}

// ---------------------------------------------------------------------------
// fusedAll: 1024 threads = two independent 512-thread halves, each one graph.
// LDS budget (147KB -> exactly 1 block/CU):
//   blkU[2][6400] u32 : xs (x rows, 64x100 f32)  OVERLAID LATER BY
//                       Asu (64x68 u32 adjacency) + Sred/Qred (8x128 f32 x2)
//   h2sA/aggsA[2][64*68] f32, Ws2[6400] f32 (W packed [i4][c][4]), b2s[64]
// Phases (S* = __syncthreads):
//   0 issue edge loads -> regs | stage x->LDS | build W,b2 in LDS      S1
//   1 encoder: lane=channel, per-lane Ws2 b128 + x broadcast -> h2s    S2
//   2 zero Asu (xs dead)                                               S3
//     LDS-atomic edge count                                            S4
//   3 agg = A @ h2                                                     S5
//   4 j-per-lane: lane owns j,j+64; rel/root rows per-lane VMEM (L2-hot),
//     agg/h2 uniform LDS broadcast; partials -> Sred/Qred              S6
//     final reduce -> Sg/Qg global (+ LDS stash for E)
//   GRID BARRIER -> D (BN stats, 128 blocks) -> GRID BARRIER -> E
// ---------------------------------------------------------------------------
__global__ __launch_bounds__(1024, 4) void fusedAll(
    const float* __restrict__ x, const int* __restrict__ ei,
    const float* __restrict__ conv_w, const float* __restrict__ conv_b,
    const float* __restrict__ fc1_w, const float* __restrict__ fc1_b,
    const float* __restrict__ rel_w, const float* __restrict__ rel_b,
    const float* __restrict__ root_w, const float* __restrict__ gamma,
    const float* __restrict__ beta, const float* __restrict__ fc2_w,
    const float* __restrict__ fc2_b, float* __restrict__ y,
    float* __restrict__ Sg, float* __restrict__ Qg, float* __restrict__ ab,
    unsigned* __restrict__ bar, int E, int G, int N, int coop) {
    __shared__ unsigned blkU[2][6400];
    __shared__ float h2sA[2][64 * CST];
    __shared__ float aggsA[2][64 * CST];
    __shared__ float Ws2[6400];
    __shared__ float b2s[64];
    __shared__ float red[32];

    const int tid = threadIdx.x;
    const int hid = tid >> 9;      // graph-half 0/1
    const int sub = tid & 511;
    const int lane = sub & 63;
    const int w2 = sub >> 6;       // wave index within half, 0..7

    // bijective XCD swizzle over block-pairs (edge-cacheline L2 locality)
    const int nb = gridDim.x;
    int qq = nb >> 3, rr = nb & 7;
    int xc = blockIdx.x & 7, oo = blockIdx.x >> 3;
    int pair = (xc < rr ? xc * (qq + 1) : rr * (qq + 1) + (xc - rr) * qq) + oo;
    const int g = pair * 2 + hid;
    const bool active = (g < G);

    float* xs = (float*)blkU[hid];
    unsigned* Asu = blkU[hid];
    float* Sred = (float*)&blkU[hid][4352];
    float* Qred = (float*)&blkU[hid][5376];
    float* h2s = h2sA[hid];
    float* aggs = aggsA[hid];

    // ---- 0. issue strided edge loads EARLY (hidden under staging/encoder) --
    const int epg = (G > 0) ? E / G : 0;
    const bool fast = (epg == 2048) && (E == G * 2048);
    int es0 = 0, es1 = 0, es2 = 0, es3 = 0;
    int ed0 = 0, ed1 = 0, ed2 = 0, ed3 = 0;
    if (fast && active) {
        int e0 = g + sub * G;
        int st = 512 * G;
        es0 = ei[e0];           ed0 = ei[E + e0];
        es1 = ei[e0 + st];      ed1 = ei[E + e0 + st];
        es2 = ei[e0 + 2 * st];  ed2 = ei[E + e0 + 2 * st];
        es3 = ei[e0 + 3 * st];  ed3 = ei[E + e0 + 3 * st];
    }

    // ---- stage x rows for both halves (coalesced float4) ----
    {
        int g0 = pair * 2;
        for (int idx = tid; idx < 3200; idx += 1024) {
            int hf = (idx >= 1600) ? 1 : 0;
            int rem = idx - hf * 1600;
            int row = rem / 25, c4 = rem - row * 25;
            if (g0 + hf < G) {
                float4 v = *(const float4*)(x +
                    ((size_t)(g0 + hf) * 64 + row) * T_LEN + c4 * 4);
                ((float4*)blkU[hf])[row * 25 + c4] = v;
            }
        }
    }

    // ---- build W packed [i4][c][4] (per-block redundant, trivial cost) ----
    for (int idx = tid; idx < 6400; idx += 1024) {
        int c = idx & 63, i = idx >> 6;
        int t0 = i - 12 > 0 ? i - 12 : 0;
        int t1 = i + 12 < T_LEN - 1 ? i + 12 : T_LEN - 1;
        float acc = 0.f;
        for (int t = t0; t <= t1; ++t)
            acc += fc1_w[t] * conv_w[c * K_LEN + (i - t + 12)];
        Ws2[((i >> 2) * 64 + c) * 4 + (i & 3)] = acc;
    }
    if (tid < 64) {
        float S = 0.f;
        for (int t = 0; t < T_LEN; ++t) S += fc1_w[t];
        b2s[tid] = conv_b[tid] * S + fc1_b[0];
    }
    __syncthreads();  // S1

    // ---- 1. encoder: lane = channel c; wave w2 handles nodes [8w2,8w2+8) --
    if (active) {
        float acc[8];
#pragma unroll
        for (int k = 0; k < 8; ++k) acc[k] = 0.f;
#pragma unroll
        for (int i4 = 0; i4 < 25; ++i4) {
            float4 wv = *(const float4*)&Ws2[(i4 * 64 + lane) * 4];  // per-lane, contiguous
#pragma unroll
            for (int k = 0; k < 8; ++k) {
                float4 xv = *(const float4*)&xs[(w2 * 8 + k) * T_LEN + i4 * 4];  // broadcast
                acc[k] += dot4(wv, xv);
            }
        }
        float bb = b2s[lane];
#pragma unroll
        for (int k = 0; k < 8; ++k)
            h2s[(w2 * 8 + k) * CST + lane] = acc[k] + bb;
    }
    __syncthreads();  // S2 (xs dead)

    // ---- 2. zero adjacency (overlays xs), then LDS-atomic edge count ----
    for (int idx = sub; idx < 4352; idx += 512) Asu[idx] = 0u;
    __syncthreads();  // S3
    if (active) {
        if (fast) {
            atomicAdd(&Asu[(ed0 & 63) * AST + (es0 & 63)], 1u);
            atomicAdd(&Asu[(ed1 & 63) * AST + (es1 & 63)], 1u);
            atomicAdd(&Asu[(ed2 & 63) * AST + (es2 & 63)], 1u);
            atomicAdd(&Asu[(ed3 & 63) * AST + (es3 & 63)], 1u);
        } else {
            for (int e = g + sub * G; e < E; e += 512 * G)
                atomicAdd(&Asu[(ei[E + e] & 63) * AST + (ei[e] & 63)], 1u);
        }
    }
    __syncthreads();  // S4

    // ---- 3. agg = A @ h2 (counts converted inline) ----
    if (active) {
        int c4 = (sub & 15) * 4;
        int n0 = sub >> 4;  // 0..31
#pragma unroll
        for (int i = 0; i < 2; ++i) {
            int n = n0 + 32 * i;
            float4 a4 = {0.f, 0.f, 0.f, 0.f};
#pragma unroll 4
            for (int s4 = 0; s4 < 16; ++s4) {
                uint4 au = *(const uint4*)&Asu[n * AST + 4 * s4];
                float a0 = (float)au.x, a1 = (float)au.y;
                float a2 = (float)au.z, a3 = (float)au.w;
                float4 h0 = *(const float4*)&h2s[(4 * s4 + 0) * CST + c4];
                float4 h1 = *(const float4*)&h2s[(4 * s4 + 1) * CST + c4];
                float4 h2v = *(const float4*)&h2s[(4 * s4 + 2) * CST + c4];
                float4 h3 = *(const float4*)&h2s[(4 * s4 + 3) * CST + c4];
                a4.x += a0 * h0.x + a1 * h1.x + a2 * h2v.x + a3 * h3.x;
                a4.y += a0 * h0.y + a1 * h1.y + a2 * h2v.y + a3 * h3.y;
                a4.z += a0 * h0.z + a1 * h1.z + a2 * h2v.z + a3 * h3.z;
                a4.w += a0 * h0.w + a1 * h1.w + a2 * h2v.w + a3 * h3.w;
            }
            *(float4*)&aggs[n * CST + c4] = a4;
        }
    }
    __syncthreads();  // S5

    // ---- 4. j-per-lane: lane owns j0=lane and j0+64; 8 nodes per thread ----
    if (active) {
        int j0 = lane;
        float acc[16];
#pragma unroll
        for (int k = 0; k < 16; ++k) acc[k] = 0.f;

        for (int mc = 0; mc < 8; ++mc) {
            // per-lane weight rows: 8 float4 VMEM (64KB total, L2-hot)
            const float4* rA = (const float4*)(rel_w + (size_t)j0 * DLAT + mc * 8);
            const float4* oA = (const float4*)(root_w + (size_t)j0 * DLAT + mc * 8);
            const float4* rB = (const float4*)(rel_w + (size_t)(j0 + 64) * DLAT + mc * 8);
            const float4* oB = (const float4*)(root_w + (size_t)(j0 + 64) * DLAT + mc * 8);
            float4 ra0 = rA[0], ra1 = rA[1];
            float4 oa0 = oA[0], oa1 = oA[1];
            float4 rb0 = rB[0], rb1 = rB[1];
            float4 ob0 = oB[0], ob1 = oB[1];
#pragma unroll 4
            for (int nn = 0; nn < 8; ++nn) {
                int n = w2 * 8 + nn;
                float4 za0 = *(const float4*)&aggs[n * CST + mc * 8];      // broadcast
                float4 za1 = *(const float4*)&aggs[n * CST + mc * 8 + 4];
                float4 zh0 = *(const float4*)&h2s[n * CST + mc * 8];
                float4 zh1 = *(const float4*)&h2s[n * CST + mc * 8 + 4];
                acc[nn] += dot4(ra0, za0) + dot4(ra1, za1) +
                           dot4(oa0, zh0) + dot4(oa1, zh1);
                acc[8 + nn] += dot4(rb0, za0) + dot4(rb1, za1) +
                               dot4(ob0, zh0) + dot4(ob1, zh1);
            }
        }
        float rbA = rel_b[j0], rbB = rel_b[j0 + 64];
        float s0 = 0.f, q0 = 0.f, s1 = 0.f, q1 = 0.f;
#pragma unroll
        for (int nn = 0; nn < 8; ++nn) {
            float oA_ = acc[nn] + rbA;
            s0 += oA_; q0 += oA_ * oA_;
            float oB_ = acc[8 + nn] + rbB;
            s1 += oB_; q1 += oB_ * oB_;
        }
        Sred[w2 * DHID + j0] = s0;       Qred[w2 * DHID + j0] = q0;
        Sred[w2 * DHID + j0 + 64] = s1;  Qred[w2 * DHID + j0 + 64] = q1;
    }
    __syncthreads();  // S6

    if (active && sub < DHID) {
        int j = sub;
        float S = 0.f, Q = 0.f;
#pragma unroll
        for (int qg = 0; qg < 8; ++qg) {
            S += Sred[qg * DHID + j];
            Q += Qred[qg * DHID + j];
        }
        Sg[(size_t)g * DHID + j] = S;
        Qg[(size_t)g * DHID + j] = Q;
        Sred[j] = S;  // stash for E (survives D: D only touches red[])
        Qred[j] = Q;
    }

    if (!coop) return;  // fallback: host runs D/E kernels

    grid_barrier(&bar[0], &bar[1], (unsigned)nb);

    // ---- D: BN stats, blocks 0..127 each own one channel ----
    if (blockIdx.x < DHID) {
        int j = blockIdx.x;
        float s = 0.f, qv = 0.f;
        for (int gg = tid; gg < G; gg += 1024) {
            s += Sg[(size_t)gg * DHID + j];
            qv += Qg[(size_t)gg * DHID + j];
        }
#pragma unroll
        for (int off = 32; off; off >>= 1) {
            s += __shfl_xor(s, off);
            qv += __shfl_xor(qv, off);
        }
        int wv = tid >> 6;
        if ((tid & 63) == 0) { red[wv] = s; red[16 + wv] = qv; }
        __syncthreads();
        if (tid == 0) {
            s = 0.f; qv = 0.f;
            for (int k = 0; k < 16; ++k) { s += red[k]; qv += red[16 + k]; }
            float inv_n = 1.f / (float)N;
            float mean = s * inv_n;
            float var = qv * inv_n - mean * mean;
            float a = rsqrtf(var + 1e-5f) * gamma[j];
            float b = beta[j] - mean * a;
            ab[j] = a;
            ab[DHID + j] = b;
        }
    }

    grid_barrier(&bar[2], &bar[3], (unsigned)nb);

    // ---- E: pooled -> log -> fc2 -> sigmoid (per half) ----
    if (active && sub < DHID) {
        int j = sub;
        float a = ab[j], b = ab[DHID + j];
        float S = Sred[j], Q = Qred[j];
        float pooled = (a * a * Q + 2.f * a * b * S) * (1.f / 64.f) + b * b;
        pooled = fmaxf(pooled, 1e-6f);
        float pl = logf(pooled);
#pragma unroll
        for (int k = 0; k < 3; ++k) {
            float v = pl * fc2_w[k * DHID + j];
#pragma unroll
            for (int off = 32; off; off >>= 1) v += __shfl_xor(v, off);
            if (lane == 0) Ws2[hid * 8 + w2 * 4 + k] = v;  // w2 in {0,1} here
        }
    }
    __syncthreads();  // S7
    if (active && sub < 3) {
        float v = Ws2[hid * 8 + sub] + Ws2[hid * 8 + 4 + sub] + fc2_b[sub];
        y[(size_t)g * 3 + sub] = 1.f / (1.f + expf(-v));
    }
}

// ---------------------------------------------------------------------------
// Fallback D/E kernels (only used if grid-pair count > 256 -> coop=0)
// ---------------------------------------------------------------------------
__global__ __launch_bounds__(256) void phaseD2(const float* __restrict__ Sg,
                                               const float* __restrict__ Qg,
                                               const float* __restrict__ gamma,
                                               const float* __restrict__ beta,
                                               float* __restrict__ ab,
                                               int G, int N) {
    int j = blockIdx.x;
    int t = threadIdx.x;
    float s = 0.f, q = 0.f;
    for (int g = t; g < G; g += 256) {
        s += Sg[g * DHID + j];
        q += Qg[g * DHID + j];
    }
#pragma unroll
    for (int off = 32; off; off >>= 1) {
        s += __shfl_xor(s, off);
        q += __shfl_xor(q, off);
    }
    __shared__ float rs[4], rq[4];
    int wv = t >> 6;
    if ((t & 63) == 0) { rs[wv] = s; rq[wv] = q; }
    __syncthreads();
    if (t == 0) {
        s = rs[0] + rs[1] + rs[2] + rs[3];
        q = rq[0] + rq[1] + rq[2] + rq[3];
        float inv_n = 1.f / (float)N;
        float mean = s * inv_n;
        float var = q * inv_n - mean * mean;
        float a = rsqrtf(var + 1e-5f) * gamma[j];
        float b = beta[j] - mean * a;
        ab[j] = a;
        ab[DHID + j] = b;
    }
}

__global__ __launch_bounds__(128) void phaseE(const float* __restrict__ Sg,
                                              const float* __restrict__ Qg,
                                              const float* __restrict__ ab,
                                              const float* __restrict__ fc2_w,
                                              const float* __restrict__ fc2_b,
                                              float* __restrict__ y) {
    int g = blockIdx.x;
    int j = threadIdx.x;
    __shared__ float ps[DHID];
    float a = ab[j], b = ab[DHID + j];
    float S = Sg[g * DHID + j], Q = Qg[g * DHID + j];
    float pooled = (a * a * Q + 2.f * a * b * S) * (1.f / 64.f) + b * b;
    pooled = fmaxf(pooled, 1e-6f);
    ps[j] = logf(pooled);
    __syncthreads();
    if (j < 3) {
        float acc = fc2_b[j];
        for (int c = 0; c < DHID; ++c) acc += ps[c] * fc2_w[j * DHID + c];
        y[g * 3 + j] = 1.f / (1.f + expf(-acc));
    }
}

// ---------------------------------------------------------------------------
extern "C" void kernel_launch(void* const* d_in, const int* in_sizes, int n_in,
                              void* d_out, int out_size, void* d_ws, size_t ws_size,
                              hipStream_t stream) {
    const float* x      = (const float*)d_in[0];
    const int*   ei     = (const int*)d_in[1];
    const float* conv_w = (const float*)d_in[3];
    const float* conv_b = (const float*)d_in[4];
    const float* fc1_w  = (const float*)d_in[5];
    const float* fc1_b  = (const float*)d_in[6];
    const float* rel_w  = (const float*)d_in[7];
    const float* rel_b  = (const float*)d_in[8];
    const float* root_w = (const float*)d_in[9];
    const float* gamma  = (const float*)d_in[10];
    const float* beta   = (const float*)d_in[11];
    const float* fc2_w  = (const float*)d_in[12];
    const float* fc2_b  = (const float*)d_in[13];
    float* y = (float*)d_out;

    int N = in_sizes[2];       // 32768
    int E = in_sizes[1] / 2;   // 1048576
    int G = N / 64;            // 512

    float* Sg = (float*)d_ws;                   // G*128
    float* Qg = Sg + (size_t)G * DHID;          // G*128
    float* ab = Qg + (size_t)G * DHID;          // 2*128
    unsigned* bar = (unsigned*)(ab + 2 * DHID); // 4 u32 (padded)

    int nb = (G + 1) / 2;
    int coop = (nb <= 256) ? 1 : 0;

    hipMemsetAsync(bar, 0, 64, stream);
    fusedAll<<<nb, 1024, 0, stream>>>(x, ei, conv_w, conv_b, fc1_w, fc1_b,
                                      rel_w, rel_b, root_w, gamma, beta,
                                      fc2_w, fc2_b, y, Sg, Qg, ab, bar,
                                      E, G, N, coop);
    if (!coop) {
        phaseD2<<<DHID, 256, 0, stream>>>(Sg, Qg, gamma, beta, ab, G, N);
        phaseE<<<G, DHID, 0, stream>>>(Sg, Qg, ab, fc2_w, fc2_b, y);
    }
}

// Round 5
// 218.088 us; speedup vs baseline: 1.1848x; 1.1848x over previous
//
#include <hip/hip_runtime.h>
#include <math.h>

#define T_LEN 100
#define K_LEN 25
#define DLAT 64
#define DHID 128
#define CST 68   // h2s/aggs row stride (floats)
#define AST 68   // adjacency row stride (u32)

__device__ __forceinline__ float dot4(float4 a, float4 b) {
    return a.x * b.x + a.y * b.y + a.z * b.z + a.w * b.w;
}

// ---------------------------------------------------------------------------
// packU (one tiny dispatch):
//  - Wm[c*100+i] = collapsed Conv1d+fc1 matrix; Wm[6400+c] = b2[c]
//  - upk[((mc*128)+j)*8+k] : interleaved rel/root rows, [mc][j][8] layout so
//    part-4 reads are lane-coalesced (lane stride 32B)
//  - bar[0] = 0 (done-counter for the last-block D/E tail)
// ---------------------------------------------------------------------------
__global__ __launch_bounds__(256) void packU(const float* __restrict__ conv_w,
                                             const float* __restrict__ conv_b,
                                             const float* __restrict__ fc1_w,
                                             const float* __restrict__ fc1_b,
                                             const float* __restrict__ rel_w,
                                             const float* __restrict__ root_w,
                                             float* __restrict__ Wm,
                                             float* __restrict__ upk,
                                             unsigned* __restrict__ bar) {
    int idx = blockIdx.x * 256 + threadIdx.x;
    if (idx < 16384) {
        int mc = idx >> 10, rem = idx & 1023;
        int j = rem >> 3, k = rem & 7;
        upk[idx] = (mc < 8) ? rel_w[j * DLAT + mc * 8 + k]
                            : root_w[j * DLAT + (mc - 8) * 8 + k];
    } else if (idx < 16384 + 6400) {
        int t2 = idx - 16384;
        int c = t2 / T_LEN, i = t2 % T_LEN;
        int t0 = i - 12 > 0 ? i - 12 : 0;
        int t1 = i + 12 < T_LEN - 1 ? i + 12 : T_LEN - 1;
        float acc = 0.f;
        for (int t = t0; t <= t1; ++t)
            acc += fc1_w[t] * conv_w[c * K_LEN + (i - t + 12)];
        Wm[t2] = acc;
    } else if (idx < 16384 + 6400 + 64) {
        int c = idx - (16384 + 6400);
        float S = 0.f;
        for (int t = 0; t < T_LEN; ++t) S += fc1_w[t];
        Wm[6400 + c] = conv_b[c] * S + fc1_b[0];
    } else if (idx == 16384 + 6400 + 64) {
        bar[0] = 0u;
    }
}

// ---------------------------------------------------------------------------
// fused: one block per graph (512 thr = 8 waves). LDS 77.8KB -> 2 blocks/CU.
//   0 issue 2048 strided edge loads -> regs; stage Wm->LDS; zero adj     S1
//   1 LDS-atomic edge count | encoder (x per-lane VMEM, W broadcast LDS) S2
//   2 agg = A @ h2 (counts converted inline)                             S3
//   3 part4: lane owns j=lane & lane+64; wave owns 8 nodes; weights via
//     coalesced upk float4 stream; z rows broadcast from LDS; acc[16]    S4
//   4 reduce -> Sg/Qg global; last-done block runs BN-stats + head (D+E)
// Deadlock-free: no block ever waits; only the LAST block does the tail.
// launch_bounds(512,4): VGPR budget 128 (no spill), 16 waves/CU pin.
// ---------------------------------------------------------------------------
__global__ __launch_bounds__(512, 4) void fused(const float* __restrict__ x,
                                                const int* __restrict__ ei,
                                                const float* __restrict__ Wm,
                                                const float* __restrict__ upk,
                                                const float* __restrict__ rel_b,
                                                const float* __restrict__ gamma,
                                                const float* __restrict__ beta,
                                                const float* __restrict__ fc2_w,
                                                const float* __restrict__ fc2_b,
                                                float* __restrict__ Sg,
                                                float* __restrict__ Qg,
                                                float* __restrict__ y,
                                                unsigned* __restrict__ bar,
                                                int E, int G, int N) {
    __shared__ float Ws[6400];           // W matrix; carved for tail after S2
    __shared__ float h2s[64 * CST];
    __shared__ float aggs[64 * CST];
    __shared__ unsigned Asu[64 * AST];

    float* Sred = Ws;                    // 1024 (post-S3 use only)
    float* Qred = Ws + 1024;             // 1024
    float* fw_s = Ws + 2048;             // 384
    float* ab_s = Ws + 2432;             // 256
    int* flag = (int*)(Ws + 2688);

    const int tid = threadIdx.x;
    const int lane = tid & 63;
    const int w2 = __builtin_amdgcn_readfirstlane(tid >> 6);  // 0..7

    // bijective XCD swizzle (m204): adjacent graphs (sharing edge cachelines)
    // land on the same XCD.
    const int nb = gridDim.x;
    int qq = nb >> 3, rr = nb & 7;
    int xc = blockIdx.x & 7, oo = blockIdx.x >> 3;
    const int g = (xc < rr ? xc * (qq + 1) : rr * (qq + 1) + (xc - rr) * qq) + oo;

    const int epg = (G > 0) ? E / G : 0;
    const bool fast = (epg == 2048) && (E == G * 2048);

    // ---- 0. issue strided edge loads EARLY ----
    int es0 = 0, es1 = 0, es2 = 0, es3 = 0;
    int ed0 = 0, ed1 = 0, ed2 = 0, ed3 = 0;
    if (fast) {
        int e0 = g + tid * G;
        int st = 512 * G;
        es0 = ei[e0];           ed0 = ei[E + e0];
        es1 = ei[e0 + st];      ed1 = ei[E + e0 + st];
        es2 = ei[e0 + 2 * st];  ed2 = ei[E + e0 + 2 * st];
        es3 = ei[e0 + 3 * st];  ed3 = ei[E + e0 + 3 * st];
    }

    // stage W into LDS (coalesced float4), zero adjacency
    for (int i = tid; i < 1600; i += 512)
        ((float4*)Ws)[i] = ((const float4*)Wm)[i];
    for (int i = tid; i < 64 * AST; i += 512) Asu[i] = 0u;
    __syncthreads();  // S1

    // ---- 1a. edge counting via LDS atomics (edge regs ready first) ----
    if (fast) {
        atomicAdd(&Asu[(ed0 & 63) * AST + (es0 & 63)], 1u);
        atomicAdd(&Asu[(ed1 & 63) * AST + (es1 & 63)], 1u);
        atomicAdd(&Asu[(ed2 & 63) * AST + (es2 & 63)], 1u);
        atomicAdd(&Asu[(ed3 & 63) * AST + (es3 & 63)], 1u);
    } else {
        for (int e = g + tid * G; e < E; e += 512 * G)
            atomicAdd(&Asu[(ei[E + e] & 63) * AST + (ei[e] & 63)], 1u);
    }

    // ---- 1b. encoder: lane=node, wave w2 -> channels [8w2,8w2+8) ----
    {
        const float4* __restrict__ xp =
            (const float4*)(x + (size_t)(g * 64 + lane) * T_LEN);
        const float* Wb = Ws + w2 * 8 * T_LEN;   // LDS, wave-uniform
        float acc[8];
#pragma unroll
        for (int c = 0; c < 8; ++c) acc[c] = 0.f;
#pragma unroll
        for (int tq = 0; tq < T_LEN / 4; ++tq) {
            float4 xv = xp[tq];
#pragma unroll
            for (int c = 0; c < 8; ++c) {
                float4 wv = *(const float4*)(Wb + c * T_LEN + tq * 4);  // broadcast
                acc[c] += dot4(xv, wv);
            }
        }
        float4 o0, o1;
        o0.x = acc[0] + Wm[6400 + w2 * 8 + 0];
        o0.y = acc[1] + Wm[6400 + w2 * 8 + 1];
        o0.z = acc[2] + Wm[6400 + w2 * 8 + 2];
        o0.w = acc[3] + Wm[6400 + w2 * 8 + 3];
        o1.x = acc[4] + Wm[6400 + w2 * 8 + 4];
        o1.y = acc[5] + Wm[6400 + w2 * 8 + 5];
        o1.z = acc[6] + Wm[6400 + w2 * 8 + 6];
        o1.w = acc[7] + Wm[6400 + w2 * 8 + 7];
        *(float4*)&h2s[lane * CST + w2 * 8] = o0;
        *(float4*)&h2s[lane * CST + w2 * 8 + 4] = o1;
    }
    __syncthreads();  // S2

    // ---- 2. agg = A @ h2 (counts converted inline) ----
    {
        int c4 = (tid & 15) * 4;
        int n0 = tid >> 4;  // 0..31
#pragma unroll
        for (int i = 0; i < 2; ++i) {
            int n = n0 + 32 * i;
            float4 a4 = {0.f, 0.f, 0.f, 0.f};
#pragma unroll 4
            for (int s4 = 0; s4 < 16; ++s4) {
                uint4 au = *(const uint4*)&Asu[n * AST + 4 * s4];
                float a0 = (float)au.x, a1 = (float)au.y;
                float a2 = (float)au.z, a3 = (float)au.w;
                float4 h0 = *(const float4*)&h2s[(4 * s4 + 0) * CST + c4];
                float4 h1 = *(const float4*)&h2s[(4 * s4 + 1) * CST + c4];
                float4 h2v = *(const float4*)&h2s[(4 * s4 + 2) * CST + c4];
                float4 h3 = *(const float4*)&h2s[(4 * s4 + 3) * CST + c4];
                a4.x += a0 * h0.x + a1 * h1.x + a2 * h2v.x + a3 * h3.x;
                a4.y += a0 * h0.y + a1 * h1.y + a2 * h2v.y + a3 * h3.y;
                a4.z += a0 * h0.z + a1 * h1.z + a2 * h2v.z + a3 * h3.z;
                a4.w += a0 * h0.w + a1 * h1.w + a2 * h2v.w + a3 * h3.w;
            }
            *(float4*)&aggs[n * CST + c4] = a4;
        }
    }
    __syncthreads();  // S3

    // ---- 3. part4: lane owns j0=lane, j1=lane+64; wave owns 8 nodes ----
    {
        const float4* up4 = (const float4*)upk;
        float accJ[16];  // [nn][jj]
#pragma unroll
        for (int k = 0; k < 16; ++k) accJ[k] = 0.f;

#pragma unroll
        for (int mc = 0; mc < 16; ++mc) {
            int ba = (mc * 128 + lane) * 2;        // float4 units, coalesced
            int bb = (mc * 128 + lane + 64) * 2;
            float4 wa0 = up4[ba], wa1 = up4[ba + 1];
            float4 wb0 = up4[bb], wb1 = up4[bb + 1];
            const float* zbase = (mc < 8) ? (aggs + mc * 8) : (h2s + (mc - 8) * 8);
#pragma unroll
            for (int nn = 0; nn < 8; ++nn) {
                const float* zr = zbase + (w2 * 8 + nn) * CST;   // wave-uniform
                float4 z0 = *(const float4*)zr;                  // broadcast
                float4 z1 = *(const float4*)(zr + 4);
                accJ[2 * nn] += dot4(wa0, z0) + dot4(wa1, z1);
                accJ[2 * nn + 1] += dot4(wb0, z0) + dot4(wb1, z1);
            }
        }

        float rb0 = rel_b[lane], rb1 = rel_b[lane + 64];
        float s0 = 0.f, q0 = 0.f, s1 = 0.f, q1 = 0.f;
#pragma unroll
        for (int nn = 0; nn < 8; ++nn) {
            float o0 = accJ[2 * nn] + rb0;
            s0 += o0; q0 += o0 * o0;
            float o1 = accJ[2 * nn + 1] + rb1;
            s1 += o1; q1 += o1 * o1;
        }
        Sred[w2 * DHID + lane] = s0;       Qred[w2 * DHID + lane] = q0;
        Sred[w2 * DHID + 64 + lane] = s1;  Qred[w2 * DHID + 64 + lane] = q1;
    }
    __syncthreads();  // S4

    if (tid < DHID) {
        float S = 0.f, Q = 0.f;
#pragma unroll
        for (int k = 0; k < 8; ++k) {
            S += Sred[k * DHID + tid];
            Q += Qred[k * DHID + tid];
        }
        Sg[(size_t)g * DHID + tid] = S;
        Qg[(size_t)g * DHID + tid] = Q;
    }
    __syncthreads();  // S5: all Sg/Qg stores issued & drained before fence

    if (tid == 0) {
        __threadfence();  // release this block's Sg/Qg
        unsigned old = __hip_atomic_fetch_add(&bar[0], 1u, __ATOMIC_ACQ_REL,
                                              __HIP_MEMORY_SCOPE_AGENT);
        *flag = (old == (unsigned)nb - 1u) ? 1 : 0;
        if (*flag) __threadfence();  // acquire all other blocks' writes
    }
    __syncthreads();
    if (!*flag) return;

    // =============== last block only: D (BN stats) + E (head) ===============
    {
        // D: 4-way split over graphs, coalesced Sg/Qg reads
        int gq = tid >> 7, j = tid & 127;
        float s = 0.f, qv = 0.f;
        for (int gi = gq; gi < G; gi += 4) {
            s += Sg[(size_t)gi * DHID + j];
            qv += Qg[(size_t)gi * DHID + j];
        }
        Sred[gq * DHID + j] = s;
        Qred[gq * DHID + j] = qv;
    }
    for (int i = tid; i < 3 * DHID; i += 512) fw_s[i] = fc2_w[i];
    __syncthreads();
    if (tid < DHID) {
        float S = Sred[tid] + Sred[DHID + tid] + Sred[2 * DHID + tid] +
                  Sred[3 * DHID + tid];
        float Q = Qred[tid] + Qred[DHID + tid] + Qred[2 * DHID + tid] +
                  Qred[3 * DHID + tid];
        float inv_n = 1.f / (float)N;
        float mean = S * inv_n;
        float var = Q * inv_n - mean * mean;
        float a = rsqrtf(var + 1e-5f) * gamma[tid];
        float b = beta[tid] - mean * a;
        ab_s[tid] = a;
        ab_s[DHID + tid] = b;
    }
    __syncthreads();

    // E: one wave per graph; lane covers j=lane and j=lane+64
    {
        float fb0 = fc2_b[0], fb1 = fc2_b[1], fb2 = fc2_b[2];
        for (int gg = w2; gg < G; gg += 8) {
            float S0 = Sg[(size_t)gg * DHID + lane];
            float Q0 = Qg[(size_t)gg * DHID + lane];
            float S1 = Sg[(size_t)gg * DHID + 64 + lane];
            float Q1 = Qg[(size_t)gg * DHID + 64 + lane];
            float a0 = ab_s[lane], b0 = ab_s[DHID + lane];
            float a1 = ab_s[64 + lane], b1 = ab_s[DHID + 64 + lane];
            float p0 = (a0 * a0 * Q0 + 2.f * a0 * b0 * S0) * (1.f / 64.f) + b0 * b0;
            float p1 = (a1 * a1 * Q1 + 2.f * a1 * b1 * S1) * (1.f / 64.f) + b1 * b1;
            float l0 = logf(fmaxf(p0, 1e-6f));
            float l1 = logf(fmaxf(p1, 1e-6f));
            float v0 = l0 * fw_s[lane] + l1 * fw_s[64 + lane];
            float v1 = l0 * fw_s[DHID + lane] + l1 * fw_s[DHID + 64 + lane];
            float v2 = l0 * fw_s[2 * DHID + lane] + l1 * fw_s[2 * DHID + 64 + lane];
#pragma unroll
            for (int off = 32; off; off >>= 1) {
                v0 += __shfl_xor(v0, off);
                v1 += __shfl_xor(v1, off);
                v2 += __shfl_xor(v2, off);
            }
            if (lane == 0) {
                y[(size_t)gg * 3 + 0] = 1.f / (1.f + expf(-(v0 + fb0)));
                y[(size_t)gg * 3 + 1] = 1.f / (1.f + expf(-(v1 + fb1)));
                y[(size_t)gg * 3 + 2] = 1.f / (1.f + expf(-(v2 + fb2)));
            }
        }
    }
}

// ---------------------------------------------------------------------------
extern "C" void kernel_launch(void* const* d_in, const int* in_sizes, int n_in,
                              void* d_out, int out_size, void* d_ws, size_t ws_size,
                              hipStream_t stream) {
    const float* x      = (const float*)d_in[0];
    const int*   ei     = (const int*)d_in[1];
    const float* conv_w = (const float*)d_in[3];
    const float* conv_b = (const float*)d_in[4];
    const float* fc1_w  = (const float*)d_in[5];
    const float* fc1_b  = (const float*)d_in[6];
    const float* rel_w  = (const float*)d_in[7];
    const float* rel_b  = (const float*)d_in[8];
    const float* root_w = (const float*)d_in[9];
    const float* gamma  = (const float*)d_in[10];
    const float* beta   = (const float*)d_in[11];
    const float* fc2_w  = (const float*)d_in[12];
    const float* fc2_b  = (const float*)d_in[13];
    float* y = (float*)d_out;

    int N = in_sizes[2];       // 32768
    int E = in_sizes[1] / 2;   // 1048576
    int G = N / 64;            // 512

    float* Sg     = (float*)d_ws;                  // G*128
    float* Qg     = Sg + (size_t)G * DHID;         // G*128
    float* Wm     = Qg + (size_t)G * DHID;         // 6400 + 64 (b2)
    float* upk    = Wm + 6464;                     // 16384
    unsigned* bar = (unsigned*)(upk + 16384);      // counter

    packU<<<90, 256, 0, stream>>>(conv_w, conv_b, fc1_w, fc1_b, rel_w, root_w,
                                  Wm, upk, bar);
    fused<<<G, 512, 0, stream>>>(x, ei, Wm, upk, rel_b, gamma, beta,
                                 fc2_w, fc2_b, Sg, Qg, y, bar, E, G, N);
}